// Round 5
// baseline (3468.204 us; speedup 1.0000x reference)
//
#include <hip/hip_runtime.h>
#include <hip/hip_bf16.h>
#include <hip/hip_cooperative_groups.h>
#include <cstdint>
#include <cstddef>

#define B_   32
#define T_   64
#define S_   128
#define EH   512
#define DH   512
#define ATT  256
#define EMBD 256
#define V_   32000
#define VO   31999
#define G3   1536

#define NATT 128
#define NGRU 64
#define NBLK 192

#define ATTN_OFF 65533952   /* 32*64*31999 */

typedef __attribute__((ext_vector_type(8))) short bf16x8;
typedef __attribute__((ext_vector_type(4))) float f32x4;

static __device__ __forceinline__ unsigned short f2bf(float f) {
    union { float f; unsigned u; } x; x.f = f;
    unsigned r = (x.u + 0x7fffu + ((x.u >> 16) & 1u)) >> 16;
    return (unsigned short)r;
}

static __device__ __forceinline__ float fast_tanh(float x) {
    float xc = fminf(fmaxf(x, -15.0f), 15.0f);
    float e = __expf(2.0f * xc);
    return (e - 1.0f) / (e + 1.0f);
}

static __device__ __forceinline__ float fast_sig(float x) {
    return 1.0f / (1.0f + __expf(-x));
}

// Hand-rolled grid barrier: no acquire anywhere (no buffer_inv -> L2 stays
// warm). Cross-block data travels via sc1 atomics; __syncthreads() drains
// vmcnt before arrival.
static __device__ __forceinline__ void gbar(unsigned* cnt, unsigned* gen,
                                            unsigned target) {
    __syncthreads();
    if (threadIdx.x == 0) {
        unsigned old = __hip_atomic_fetch_add(cnt, 1u, __ATOMIC_RELEASE,
                                              __HIP_MEMORY_SCOPE_AGENT);
        if (old == (unsigned)(NBLK - 1)) {
            __hip_atomic_store(cnt, 0u, __ATOMIC_RELAXED, __HIP_MEMORY_SCOPE_AGENT);
            __hip_atomic_store(gen, target, __ATOMIC_RELEASE, __HIP_MEMORY_SCOPE_AGENT);
        } else {
            while (__hip_atomic_load(gen, __ATOMIC_RELAXED,
                                     __HIP_MEMORY_SCOPE_AGENT) != target) {}
        }
    }
    __syncthreads();
}

// ---------------------------------------------------------------------------
// Prep: transpose (512,256) -> (256,512) fp32   (used for W_enc and W_dec)
__global__ void k_trans_512x256(const float* __restrict__ in, float* __restrict__ out) {
    __shared__ float tile[32][33];
    int c0 = blockIdx.x * 32;
    int r0 = blockIdx.y * 32;
    int tx = threadIdx.x, ty = threadIdx.y;
#pragma unroll
    for (int q = 0; q < 4; q++)
        tile[ty + q*8][tx] = in[(r0 + ty + q*8) * 256 + c0 + tx];
    __syncthreads();
#pragma unroll
    for (int q = 0; q < 4; q++)
        out[(c0 + ty + q*8) * 512 + r0 + tx] = tile[tx][ty + q*8];
}

// ---------------------------------------------------------------------------
// Prep: W_fc (512 x 31999) fp32 -> W_fcT (32000 x 512) bf16, pad row zeroed
__global__ void k_wfc(const float* __restrict__ wfc, unsigned short* __restrict__ outT) {
    __shared__ float tile[32][33];
    int n0 = blockIdx.x * 32;
    int k0 = blockIdx.y * 32;
    int tx = threadIdx.x, ty = threadIdx.y;
#pragma unroll
    for (int q = 0; q < 4; q++) {
        int k = k0 + ty + q*8;
        int n = n0 + tx;
        tile[ty + q*8][tx] = (n < VO) ? wfc[(size_t)k * VO + n] : 0.0f;
    }
    __syncthreads();
#pragma unroll
    for (int q = 0; q < 4; q++) {
        int n = n0 + ty + q*8;
        int k = k0 + tx;
        outT[(size_t)n * 512 + k] = f2bf(tile[tx][ty + q*8]);
    }
}

// ---------------------------------------------------------------------------
// Prep: pack GRU weights into MFMA B-fragment order, bf16.
// idx = (((j*32 + kc)*4 + q)*64 + lane)*8 + e
__global__ void k_wpack(const float* __restrict__ W_ih, const float* __restrict__ W_hh,
                        unsigned short* __restrict__ Wp) {
    int idx = blockIdx.x * 256 + threadIdx.x;
    int e    = idx & 7;
    int lane = (idx >> 3) & 63;
    int q    = (idx >> 9) & 3;
    int kc   = (idx >> 11) & 31;
    int j    = idx >> 16;
    int io = lane & 15, ko = lane >> 4;
    int i = j * 16 + io;
    int k = kc * 32 + ko * 8 + e;
    int n = (q == 0) ? i : (q == 1) ? (512 + i) : (1024 + i);
    float val;
    if (k < 512) {
        val = (q == 3) ? 0.0f : W_ih[(size_t)n * 768 + 256 + k];
    } else {
        val = (q == 2) ? 0.0f : W_hh[(size_t)n * 512 + (k - 512)];
    }
    Wp[idx] = f2bf(val);
}

// ---------------------------------------------------------------------------
// Prep: h0 = decoder_init (fp32 row-major) and X-fragment h-half of Xf0;
// zeroes barrier state + energy counters (graph-capture safe, every launch).
__global__ void k_hinit2(const float* __restrict__ di, float* __restrict__ h32,
                         unsigned short* __restrict__ Xf0, unsigned* __restrict__ bar) {
    int idx = blockIdx.x * 256 + threadIdx.x;   // 16384
    float val = di[idx];
    h32[idx] = val;
    int b = idx >> 9, i = idx & 511;
    int mt = b >> 4, io = b & 15;
    int kc = 16 + (i >> 5), ko = (i >> 3) & 3, e = i & 7;
    Xf0[((((mt * 32 + kc) * 64) + ko * 16 + io) << 3) + e] = f2bf(val);
    if (idx < 64) bar[idx] = 0u;
}

// ---------------------------------------------------------------------------
// Prep: enc_proj (4096 x 256) = encoder_outputs (4096 x 512) @ W_enc
__global__ __launch_bounds__(256) void k_encproj(const float* __restrict__ enc,
                                                 const float* __restrict__ WencT,
                                                 float* __restrict__ ep) {
    int row0 = blockIdx.x * 16;
    int n = threadIdx.x;
    const float* wr = WencT + (size_t)n * 512;
    float acc[16];
#pragma unroll
    for (int r = 0; r < 16; r++) acc[r] = 0.0f;
    for (int k = 0; k < 512; k += 4) {
        float4 w = *(const float4*)(wr + k);
#pragma unroll
        for (int r = 0; r < 16; r++) {
            float4 x = *(const float4*)(enc + (size_t)(row0 + r) * 512 + k);
            acc[r] += x.x * w.x + x.y * w.y + x.z * w.z + x.w * w.w;
        }
    }
#pragma unroll
    for (int r = 0; r < 16; r++)
        ep[(size_t)(row0 + r) * 256 + n] = acc[r];
}

// ---------------------------------------------------------------------------
// Prep: gx_emb (2048 x 1536) = embedding[y] @ W_ih[:, :256]^T + b_ih
__global__ __launch_bounds__(256) void k_gxemb(const int* __restrict__ y,
                                               const float* __restrict__ embt,
                                               const float* __restrict__ W_ih,
                                               const float* __restrict__ bih,
                                               float* __restrict__ gx) {
    int row0 = blockIdx.y * 16;
    int col = blockIdx.x * 256 + threadIdx.x;
    const float* wr = W_ih + (size_t)col * 768;
    float acc[16];
#pragma unroll
    for (int r = 0; r < 16; r++) acc[r] = 0.0f;
    for (int k = 0; k < 256; k += 4) {
        float4 w = *(const float4*)(wr + k);
#pragma unroll
        for (int r = 0; r < 16; r++) {
            const float* xr = embt + (size_t)y[row0 + r] * 256 + k;  // uniform
            float4 x = *(const float4*)xr;
            acc[r] += x.x * w.x + x.y * w.y + x.z * w.z + x.w * w.w;
        }
    }
    float bv = bih[col];
#pragma unroll
    for (int r = 0; r < 16; r++)
        gx[(size_t)(row0 + r) * G3 + col] = acc[r] + bv;
}

// ---------------------------------------------------------------------------
// Persistent cooperative kernel, 192 blocks x 512 threads.
//  blocks [0,128): attention, (b = bid>>2, nu = bid&3): 64-dim dec slice,
//    energy partial over its dims (exchanged via monotonic ecnt[b] + epart),
//    redundant softmax, 128-dim context slice -> X ctx fragments.
//  blocks [128,192): GRU, (j = ..>>1, kh = ..&1): output dims [16j,16j+16)
//    per gate, K-half kh (kh0: ctx K + q2; kh1: h K + q3). kh1 runs during
//    phase A (only needs h(t-1)), posts partials to gpart[j]; mid-step
//    barrier orders them; kh0 runs phase B, adds partner partials, gates.
__global__ __launch_bounds__(512) void k_recur(
        const float* __restrict__ WdecT, const float* __restrict__ ep,
        const float* __restrict__ v, const int* __restrict__ mask,
        const float* __restrict__ enc, float* __restrict__ attn_out,
        const unsigned short* __restrict__ Wp, const float* __restrict__ gx_emb,
        const float* __restrict__ b_hh, const float* __restrict__ dinit,
        unsigned short* __restrict__ Xf0, unsigned short* __restrict__ Xf1,
        float* __restrict__ h32, unsigned short* __restrict__ Hall,
        unsigned* __restrict__ bar, float* __restrict__ epart,
        float* __restrict__ gpart) {
    __shared__ char smem[96512];
    __shared__ unsigned g0s;

    int bid = blockIdx.x, tid = threadIdx.x;
    int w = tid >> 6, lane = tid & 63;
    unsigned* bcnt = bar;
    unsigned* bgen = bar + 1;
    unsigned* ecnt = bar + 8;

    const bool is_att = (bid < NATT);

    // attention carve
    float* hbuf = (float*)smem;                 // 512 f
    float* pdec = (float*)(smem + 2048);        // [64][9]
    float* decs = (float*)(smem + 4352);        // 64 f
    float* es   = (float*)(smem + 4608);        // 128 f
    float* redv = (float*)(smem + 5120);        // 2 f
    float* vsl  = (float*)(smem + 5152);        // 64 f
    int*   mskl = (int*)(smem + 5408);          // 128 i
    float* pctx = (float*)(smem + 5920);        // [4][129]
    // gru carve
    uint4* wg   = (uint4*)smem;                 // 48 KB
    uint4* xst  = (uint4*)(smem + 49152);       // 32 KB
    float* pacc = (float*)(smem + 81920);       // 1536 f
    float* gprt = (float*)(smem + 88064);       // 1536 f
    float* hloc = (float*)(smem + 94208);       // 512 f
    float* bhsl = (float*)(smem + 96256);       // 48 f

    int b = 0, nu = 0, j = 0, kh = 0;
    if (is_att) {
        b = bid >> 2; nu = bid & 3;
        if (tid < 64)  vsl[tid] = v[nu * 64 + tid];
        if (tid < 128) mskl[tid] = mask[b * 128 + tid];
    } else {
        int g_ = bid - NATT; j = g_ >> 1; kh = g_ & 1;
        for (int c = tid; c < 3072; c += 512) {    // 16-B chunks of weight slice
            int gg = c >> 10, kcl = (c >> 6) & 15, ln = c & 63;
            int q = (gg == 2) ? (kh ? 3 : 2) : gg;
            int kc = kh * 16 + kcl;
            wg[(gg * 16 + kcl) * 64 + ln] =
                ((const uint4*)Wp)[(size_t)((j * 32 + kc) * 4 + q) * 64 + ln];
        }
        hloc[tid] = dinit[(size_t)(tid >> 4) * 512 + j * 16 + (tid & 15)];
        if (tid < 48) bhsl[tid] = b_hh[(tid >> 4) * 512 + j * 16 + (tid & 15)];
    }
    if (tid == 0)
        g0s = __hip_atomic_load(bgen, __ATOMIC_RELAXED, __HIP_MEMORY_SCOPE_AGENT);
    __syncthreads();
    unsigned bt = g0s;

    const float* epb  = ep  + (size_t)b * 128 * 256;
    const float* encb = enc + (size_t)b * 128 * 512;
    int mtb = b >> 4, iob = b & 15;

    for (int t = 0; t < T_; t++) {
        unsigned short* Xcur = (t & 1) ? Xf1 : Xf0;
        unsigned short* Xnxt = (t & 1) ? Xf0 : Xf1;
        float ge_r = 0.f, ge_z = 0.f, ge_n = 0.f;

        if (is_att) {
            // ---- h(t-1) load ----
            hbuf[tid] = __hip_atomic_load(&h32[b * 512 + tid], __ATOMIC_RELAXED,
                                          __HIP_MEMORY_SCOPE_AGENT);
            __syncthreads();
            // ---- dec slice: dim = nu*64+lane, K-chunk = wave ----
            {
                const float* wr = WdecT + (size_t)(nu * 64 + lane) * 512 + w * 64;
                const float* hb = hbuf + w * 64;
                float acc = 0.f;
#pragma unroll
                for (int k = 0; k < 64; k += 4) {
                    float4 wv = *(const float4*)(wr + k);
                    acc += wv.x * hb[k] + wv.y * hb[k + 1]
                         + wv.z * hb[k + 2] + wv.w * hb[k + 3];
                }
                pdec[lane * 9 + w] = acc;
            }
            __syncthreads();
            if (tid < 64) {
                float a = 0.f;
#pragma unroll
                for (int kp = 0; kp < 8; kp++) a += pdec[tid * 9 + kp];
                decs[tid] = a;
            }
            __syncthreads();
            // ---- energy partial: wave w -> s = w*16..+15, lane -> dim ----
            {
                float dq = decs[lane], vq = vsl[lane];
#pragma unroll
                for (int si = 0; si < 16; si++) {
                    int s = w * 16 + si;
                    float e = fast_tanh(epb[(size_t)s * 256 + nu * 64 + lane] + dq) * vq;
#pragma unroll
                    for (int o = 32; o; o >>= 1) e += __shfl_xor(e, o);
                    if (lane == 0)
                        __hip_atomic_store(&epart[((b << 2) + nu) * 128 + s], e,
                                           __ATOMIC_RELAXED, __HIP_MEMORY_SCOPE_AGENT);
                }
            }
            __syncthreads();   // drain partial stores
            if (tid == 0) {
                __hip_atomic_fetch_add(&ecnt[b], 1u, __ATOMIC_RELEASE,
                                       __HIP_MEMORY_SCOPE_AGENT);
                unsigned tgt = 4u * (unsigned)(t + 1);
                while (__hip_atomic_load(&ecnt[b], __ATOMIC_RELAXED,
                                         __HIP_MEMORY_SCOPE_AGENT) < tgt) {}
            }
            __syncthreads();
            if (tid < 128) {
                const float* epr = epart + (size_t)(b << 2) * 128 + tid;
                float e = __hip_atomic_load(epr,       __ATOMIC_RELAXED, __HIP_MEMORY_SCOPE_AGENT)
                        + __hip_atomic_load(epr + 128, __ATOMIC_RELAXED, __HIP_MEMORY_SCOPE_AGENT)
                        + __hip_atomic_load(epr + 256, __ATOMIC_RELAXED, __HIP_MEMORY_SCOPE_AGENT)
                        + __hip_atomic_load(epr + 384, __ATOMIC_RELAXED, __HIP_MEMORY_SCOPE_AGENT);
                es[tid] = (mskl[tid] == 0) ? -1e9f : e;
            }
            __syncthreads();
            // ---- softmax over 128 (redundant in all 4 slices) ----
            if (tid < 64) {
                float a = fmaxf(es[tid], es[tid + 64]);
#pragma unroll
                for (int o = 32; o; o >>= 1) a = fmaxf(a, __shfl_xor(a, o));
                if (tid == 0) redv[0] = a;
            }
            __syncthreads();
            float mx = redv[0];
            if (tid < 128) es[tid] = __expf(es[tid] - mx);
            __syncthreads();
            if (tid < 64) {
                float a = es[tid] + es[tid + 64];
#pragma unroll
                for (int o = 32; o; o >>= 1) a += __shfl_xor(a, o);
                if (tid == 0) redv[1] = a;
            }
            __syncthreads();
            float inv = 1.0f / redv[1];
            if (tid < 128) {
                float aw = es[tid] * inv;
                es[tid] = aw;
                if (nu == 0)
                    attn_out[(size_t)b * (T_ * S_) + t * S_ + tid] = aw;
            }
            __syncthreads();
            // ---- context slice: d = nu*128 + d2, s-chunk = sh ----
            {
                int d2 = tid & 127, sh = tid >> 7;
                const float* eb = encb + nu * 128 + d2;
                float a1 = 0.f;
#pragma unroll 8
                for (int s = sh * 32; s < sh * 32 + 32; s++)
                    a1 += es[s] * eb[(size_t)s * 512];
                pctx[sh * 129 + d2] = a1;
            }
            __syncthreads();
            if (tid < 128) {
                float c = pctx[tid] + pctx[129 + tid] + pctx[258 + tid] + pctx[387 + tid];
                unsigned short mybf = f2bf(c);
                int oth = __shfl_down((int)mybf, 1);
                int d = nu * 128 + tid;
                int hw = ((mtb * 32 + (d >> 5)) * 64 + ((d >> 3) & 3) * 16 + iob) * 8 + (d & 7);
                if (!(tid & 1)) {
                    unsigned pk = ((unsigned)mybf & 0xffffu) | ((unsigned)oth << 16);
                    __hip_atomic_store((unsigned*)Xcur + (hw >> 1), pk,
                                       __ATOMIC_RELAXED, __HIP_MEMORY_SCOPE_AGENT);
                }
            }
        } else if (kh == 1) {
            // ---- GRU h-half partials during phase A (needs only h(t-1)) ----
            const unsigned long long* Xg = (const unsigned long long*)Xcur;
#pragma unroll
            for (int u = 0; u < 8; u++) {
                int lw = u * 512 + tid;
                int mtl = lw >> 11, r = lw & 2047;
                int kcl = r >> 7, rr = r & 127;
                size_t gw = (size_t)((mtl * 32 + 16 + kcl) * 128) + rr;
                ((unsigned long long*)xst)[lw] =
                    __hip_atomic_load(Xg + gw, __ATOMIC_RELAXED, __HIP_MEMORY_SCOPE_AGENT);
            }
            __syncthreads();
            if (w < 6) {
                int mt = w & 1, gg = w >> 1;
                f32x4 acc = {0.f, 0.f, 0.f, 0.f};
                const uint4* xw  = xst + mt * 16 * 64;
                const uint4* wgg = wg + gg * 16 * 64;
#pragma unroll
                for (int kcl = 0; kcl < 16; kcl++) {
                    uint4 a  = xw[kcl * 64 + lane];
                    uint4 bv = wgg[kcl * 64 + lane];
                    acc = __builtin_amdgcn_mfma_f32_16x16x32_bf16(
                        *(const bf16x8*)&a, *(const bf16x8*)&bv, acc, 0, 0, 0);
                }
                int row = lane >> 4, col = lane & 15;
                float* gp = gpart + (size_t)j * 1536;
#pragma unroll
                for (int reg = 0; reg < 4; reg++)
                    __hip_atomic_store(&gp[((gg * 2 + mt) * 16 + row * 4 + reg) * 16 + col],
                                       acc[reg], __ATOMIC_RELAXED, __HIP_MEMORY_SCOPE_AGENT);
            }
        } else {
            // kh==0: prefetch this step's gx_emb gate values (used in gating)
            int gb = tid >> 4, gi = j * 16 + (tid & 15);
            const float* g = gx_emb + (size_t)(gb * 64 + t) * G3;
            ge_r = g[gi]; ge_z = g[512 + gi]; ge_n = g[1024 + gi];
        }

        gbar(bcnt, bgen, ++bt);   // mid-step: ctx(t) + kh1 partials visible

        if (!is_att && kh == 0) {
            // ---- GRU ctx-half + gating ----
            const unsigned long long* Xg = (const unsigned long long*)Xcur;
#pragma unroll
            for (int u = 0; u < 8; u++) {
                int lw = u * 512 + tid;
                int mtl = lw >> 11, r = lw & 2047;
                int kcl = r >> 7, rr = r & 127;
                size_t gw = (size_t)((mtl * 32 + kcl) * 128) + rr;
                ((unsigned long long*)xst)[lw] =
                    __hip_atomic_load(Xg + gw, __ATOMIC_RELAXED, __HIP_MEMORY_SCOPE_AGENT);
            }
            __syncthreads();
            if (w < 6) {
                int mt = w & 1, gg = w >> 1;
                f32x4 acc = {0.f, 0.f, 0.f, 0.f};
                const uint4* xw  = xst + mt * 16 * 64;
                const uint4* wgg = wg + gg * 16 * 64;
#pragma unroll
                for (int kcl = 0; kcl < 16; kcl++) {
                    uint4 a  = xw[kcl * 64 + lane];
                    uint4 bv = wgg[kcl * 64 + lane];
                    acc = __builtin_amdgcn_mfma_f32_16x16x32_bf16(
                        *(const bf16x8*)&a, *(const bf16x8*)&bv, acc, 0, 0, 0);
                }
                int row = lane >> 4, col = lane & 15;
#pragma unroll
                for (int reg = 0; reg < 4; reg++)
                    pacc[((gg * 2 + mt) * 16 + row * 4 + reg) * 16 + col] = acc[reg];
            }
            // partner partials (posted before mid barrier)
            {
                const float* gp = gpart + (size_t)j * 1536;
#pragma unroll
                for (int u = 0; u < 3; u++) {
                    int i5 = u * 512 + tid;
                    gprt[i5] = __hip_atomic_load(&gp[i5], __ATOMIC_RELAXED,
                                                 __HIP_MEMORY_SCOPE_AGENT);
                }
            }
            __syncthreads();
            // gating: thread = (batch gb, dim i2)
            {
                int gb = tid >> 4, i2 = tid & 15;
                int mt = gb >> 4, row = gb & 15;
                int base0 = ((0 * 2 + mt) * 16 + row) * 16 + i2;
                int base1 = ((1 * 2 + mt) * 16 + row) * 16 + i2;
                int base2 = ((2 * 2 + mt) * 16 + row) * 16 + i2;
                float rp = pacc[base0] + gprt[base0];
                float zp = pacc[base1] + gprt[base1];
                float nx = pacc[base2];          // own q2 (ctx K)
                float nh = gprt[base2];          // partner q3 (h K)
                float r = fast_sig(ge_r + rp + bhsl[i2]);
                float z = fast_sig(ge_z + zp + bhsl[16 + i2]);
                float n = fast_tanh(ge_n + nx + r * (nh + bhsl[32 + i2]));
                float prev = hloc[tid];
                float hv = (1.0f - z) * n + z * prev;
                hloc[tid] = hv;
                int gi = j * 16 + i2;
                __hip_atomic_store(&h32[gb * 512 + gi], hv, __ATOMIC_RELAXED,
                                   __HIP_MEMORY_SCOPE_AGENT);
                unsigned short hb16 = f2bf(hv);
                int oth = __shfl_down((int)hb16, 1);
                int hw = ((mt * 32 + 16 + (gi >> 5)) * 64 + ((gi >> 3) & 3) * 16 + row) * 8 + (gi & 7);
                if (!(tid & 1)) {
                    unsigned pk = ((unsigned)hb16 & 0xffffu) | ((unsigned)oth << 16);
                    __hip_atomic_store((unsigned*)Xnxt + (hw >> 1), pk,
                                       __ATOMIC_RELAXED, __HIP_MEMORY_SCOPE_AGENT);
                }
                Hall[(size_t)(gb * 64 + t) * 512 + gi] = hb16;
            }
        }

        gbar(bcnt, bgen, ++bt);   // end-of-step: h(t) visible
    }
}

// ---------------------------------------------------------------------------
// FC: out (2048 x 31999) = H_all (2048x512) bf16 @ W_fcT^T bf16 + b_fc
// 128x128 tiles, BK=32. Epilogue stages C in LDS and writes contiguous rows.
__global__ __launch_bounds__(256) void k_fc(const unsigned short* __restrict__ A,
                                            const unsigned short* __restrict__ Bt,
                                            const float* __restrict__ bias,
                                            float* __restrict__ out) {
    __shared__ char smem[65536];
    unsigned short* Abuf = (unsigned short*)smem;            // 128*40 = 10240 B
    unsigned short* Bbuf = (unsigned short*)(smem + 10240);  // 10240 B
    int tid = threadIdx.x;
    int n0 = blockIdx.x * 128, m0 = blockIdx.y * 128;
    int w = tid >> 6, lane = tid & 63;
    int wm = w >> 1, wn = w & 1;
    int io = lane & 15, ko = lane >> 4;

    const uint4* Ag = (const uint4*)A;
    const uint4* Bg = (const uint4*)Bt;

    f32x4 z4 = {0.f, 0.f, 0.f, 0.f};
    f32x4 acc[4][4];
#pragma unroll
    for (int a = 0; a < 4; a++)
#pragma unroll
        for (int b = 0; b < 4; b++) acc[a][b] = z4;

    for (int k0 = 0; k0 < 512; k0 += 32) {
        uint4 av[2], bv[2];
#pragma unroll
        for (int u = 0; u < 2; u++) {
            int c = tid + u * 256;
            int r = c >> 2, ch = c & 3;
            av[u] = Ag[(size_t)(m0 + r) * 64 + (k0 >> 3) + ch];
            bv[u] = Bg[(size_t)(n0 + r) * 64 + (k0 >> 3) + ch];
        }
        __syncthreads();
#pragma unroll
        for (int u = 0; u < 2; u++) {
            int c = tid + u * 256;
            int r = c >> 2, ch = c & 3;
            *(uint4*)((char*)Abuf + r * 80 + ch * 16) = av[u];
            *(uint4*)((char*)Bbuf + r * 80 + ch * 16) = bv[u];
        }
        __syncthreads();
        bf16x8 af[4], bf[4];
#pragma unroll
        for (int s = 0; s < 4; s++) {
            af[s] = *(const bf16x8*)((char*)Abuf + (wm * 64 + s * 16 + io) * 80 + ko * 16);
            bf[s] = *(const bf16x8*)((char*)Bbuf + (wn * 64 + s * 16 + io) * 80 + ko * 16);
        }
#pragma unroll
        for (int sm = 0; sm < 4; sm++)
#pragma unroll
            for (int sn = 0; sn < 4; sn++)
                acc[sm][sn] = __builtin_amdgcn_mfma_f32_16x16x32_bf16(af[sm], bf[sn], acc[sm][sn], 0, 0, 0);
    }

    __syncthreads();
    float* Cst = (float*)smem;   // 128 x 128 fp32 = 64 KB
#pragma unroll
    for (int sm = 0; sm < 4; sm++)
#pragma unroll
        for (int sn = 0; sn < 4; sn++) {
            int cc = wn * 64 + sn * 16 + io;
#pragma unroll
            for (int reg = 0; reg < 4; reg++) {
                int rr = wm * 64 + sm * 16 + ko * 4 + reg;
                Cst[rr * 128 + cc] = acc[sm][sn][reg];
            }
        }
    __syncthreads();
    {
        int c = tid & 127, rh = tid >> 7;
        int ng = n0 + c;
        if (ng < VO) {
            float bv = bias[ng];
#pragma unroll 8
            for (int i = 0; i < 64; i++) {
                int r = i * 2 + rh;
                out[(size_t)(m0 + r) * VO + ng] = Cst[r * 128 + c] + bv;
            }
        }
    }
}

// ---------------------------------------------------------------------------
extern "C" void kernel_launch(void* const* d_in, const int* in_sizes, int n_in,
                              void* d_out, int out_size, void* d_ws, size_t ws_size,
                              hipStream_t stream) {
    const int*   y      = (const int*)d_in[0];
    const float* enc    = (const float*)d_in[1];
    const float* dinit  = (const float*)d_in[2];
    const int*   mask   = (const int*)d_in[3];
    const float* embt   = (const float*)d_in[4];
    const float* W_enc  = (const float*)d_in[5];
    const float* W_dec  = (const float*)d_in[6];
    const float* v      = (const float*)d_in[7];
    const float* W_ih   = (const float*)d_in[8];
    const float* W_hh   = (const float*)d_in[9];
    const float* b_ih   = (const float*)d_in[10];
    const float* b_hh   = (const float*)d_in[11];
    const float* W_fc   = (const float*)d_in[12];
    const float* b_fc   = (const float*)d_in[13];
    float* out = (float*)d_out;

    char* ws = (char*)d_ws;
    size_t o = 0;
    float* enc_proj = (float*)(ws + o);          o += (size_t)4096 * 256 * 4;
    float* gx_emb   = (float*)(ws + o);          o += (size_t)2048 * 1536 * 4;
    float* WencT    = (float*)(ws + o);          o += (size_t)256 * 512 * 4;
    float* WdecT    = (float*)(ws + o);          o += (size_t)256 * 512 * 4;
    unsigned short* Wp   = (unsigned short*)(ws + o); o += (size_t)2097152 * 2;
    unsigned short* WfcT = (unsigned short*)(ws + o); o += (size_t)32000 * 512 * 2;
    unsigned short* Hall = (unsigned short*)(ws + o); o += (size_t)2048 * 512 * 2;
    unsigned short* Xf0  = (unsigned short*)(ws + o); o += (size_t)32768 * 2;
    unsigned short* Xf1  = (unsigned short*)(ws + o); o += (size_t)32768 * 2;
    float* h32 = (float*)(ws + o);               o += (size_t)32 * 512 * 4;
    unsigned* bar = (unsigned*)(ws + o);         o += 256;
    float* epart = (float*)(ws + o);             o += (size_t)32 * 4 * 128 * 4;
    float* gpart = (float*)(ws + o);             o += (size_t)32 * 1536 * 4;

    // --- prep ---
    k_trans_512x256<<<dim3(8, 16), dim3(32, 8), 0, stream>>>(W_enc, WencT);
    k_trans_512x256<<<dim3(8, 16), dim3(32, 8), 0, stream>>>(W_dec, WdecT);
    k_wfc<<<dim3(1000, 16), dim3(32, 8), 0, stream>>>(W_fc, WfcT);
    k_wpack<<<8192, 256, 0, stream>>>(W_ih, W_hh, Wp);
    k_hinit2<<<64, 256, 0, stream>>>(dinit, h32, Xf0, bar);
    k_encproj<<<256, 256, 0, stream>>>(enc, WencT, enc_proj);
    k_gxemb<<<dim3(6, 128), 256, 0, stream>>>(y, embt, W_ih, b_ih, gx_emb);

    float* attn_out = out + ATTN_OFF;

    // --- recurrence: role-specialized cooperative kernel, 192 blocks ---
    {
        const float* WdecT_c = WdecT; const float* ep_c = enc_proj;
        const unsigned short* Wp_c = Wp; const float* gx_c = gx_emb;
        void* args[] = {
            (void*)&WdecT_c, (void*)&ep_c, (void*)&v, (void*)&mask,
            (void*)&enc, (void*)&attn_out, (void*)&Wp_c, (void*)&gx_c,
            (void*)&b_hh, (void*)&dinit, (void*)&Xf0, (void*)&Xf1,
            (void*)&h32, (void*)&Hall, (void*)&bar, (void*)&epart,
            (void*)&gpart
        };
        hipLaunchCooperativeKernel((void*)k_recur, dim3(NBLK), dim3(512),
                                   args, 0, stream);
    }

    // --- batched FC over all (b,t) ---
    k_fc<<<dim3(250, 16), 256, 0, stream>>>(Hall, WfcT, b_fc, out);
}